// Round 12
// baseline (235.254 us; speedup 1.0000x reference)
//
#include <hip/hip_runtime.h>

// YOLO layer: (64, 3*85, 44, 44) -> (64, 3*44*44, 85), fp32.
// R3-R9: five structures all 79-87 us (~2.4 TB/s beyond-L2), invariant to:
// bank conflicts (R4), barriers (R5), NT stores (R6), 64B vs 256B granules
// (R5 +7%), software pipelining + counted vmcnt (R9), occupancy 29-62% (R9).
// Remaining un-probed axis vs m13's 6.3 TB/s copy: DRAM page locality of the
// read stream -- each 7744B-strided channel row yields only TILE*4 contiguous
// bytes per block. R10: TILE=256 -> 1KB per channel row per block (4x R6),
// issued back-to-back so the DRAM scheduler merges same-page requests.
// 1024-thread one-shot blocks, 87KB LDS, 1 block/CU (50% occ cap -- R9 says
// occupancy doesn't matter here). Lane map keeps 16 lanes/channel (4x256B
// segments/instr) so LDS transpose writes stay 2-way max; an all-lanes-one-
// channel map would pin bank mod 4 -> 8-way.
// R10/R11 resubmits: GPU acquisition timeouts, no data.

#define BSZ      64
#define NA       3
#define NC       80
#define GRID     44
#define SPATIAL  (GRID * GRID)        // 1936
#define CH       (5 + NC)             // 85
#define TILE     256
#define TPB      8                    // ceil(1936/256); last tile valid=144
#define NWG      (BSZ * NA * TPB)     // 1536 (divisible by 8)
#define NXCD     8
#define CHUNK    (NWG / NXCD)         // 192
#define NTHR     1024
#define NF       (CH * (TILE / 4))    // 5440 float4 slots per tile
#define NITER    ((NF + NTHR - 1) / NTHR)   // 6
#define STRIDE_F 8.0f                 // 352/44; cancels /STRIDE in scaled anchors

typedef float vfloat4 __attribute__((ext_vector_type(4)));

__device__ __forceinline__ float sigf(float x) {
    return 1.0f / (1.0f + __expf(-x));
}

__global__ __launch_bounds__(NTHR, 4)
void yolo_kernel(const float* __restrict__ in, float* __restrict__ out) {
    __shared__ float tile[TILE * CH];     // 87,040 B packed [s][c]

    // XCD-chunked swizzle (bijective since NWG%8==0).
    const int bid0 = blockIdx.x;
    const int bid  = (bid0 % NXCD) * CHUNK + bid0 / NXCD;

    const int t   = bid % TPB;
    const int ba  = bid / TPB;            // b*NA + a
    const int a   = ba % NA;

    const int s0    = t * TILE;
    const int valid = min(TILE, SPATIAL - s0);   // 256, or 144 on last tile

    const float aw = (a == 0) ? 10.0f : (a == 1) ? 16.0f : 33.0f;
    const float ah = (a == 0) ? 13.0f : (a == 1) ? 30.0f : 23.0f;

    const int tid = threadIdx.x;
    const float* inbase = in + (size_t)ba * CH * SPATIAL + s0;

    // ---- phase 1a: issue ALL global loads first ----
    // f -> (qhi, c, q4): 16 lanes/channel per instr (256B segments), but the
    // block covers q=0..63 per channel => 1KB consecutive per channel row.
    // Unpredicated, clamped in-bounds (counted vmcnt; tail re-reads harmless).
    float4 v[NITER];
    #pragma unroll
    for (int i = 0; i < NITER; ++i) {
        int f   = tid + i * NTHR;
        int g   = f / (CH * 16);          // quad-group 0..3 (4 on overflow)
        int rem = f - g * (CH * 16);
        int c   = min(rem >> 4, CH - 1);
        int q   = g * 16 + (rem & 15);    // 0..79 on overflow
        int off = min(q * 4, valid - 4);  // clamp: tail tile & overflow
        v[i] = *(const float4*)(inbase + (size_t)c * SPATIAL + off);
    }

    // ---- phase 1b: transform + LDS transpose write (packed [s][c]) ----
    #pragma unroll
    for (int i = 0; i < NITER; ++i) {
        int f   = tid + i * NTHR;
        int g   = f / (CH * 16);
        int rem = f - g * (CH * 16);
        int c   = rem >> 4;
        int q   = g * 16 + (rem & 15);
        if (f >= NF || q * 4 >= valid) continue;
        float r[4] = {v[i].x, v[i].y, v[i].z, v[i].w};
        #pragma unroll
        for (int j = 0; j < 4; ++j) {
            int   sl = q * 4 + j;         // local spatial (0..255)
            int   gs = s0 + sl;           // global spatial
            float x  = r[j];
            float o;
            if (c == 0)      o = (sigf(x) + (float)(gs % GRID)) * STRIDE_F;
            else if (c == 1) o = (sigf(x) + (float)(gs / GRID)) * STRIDE_F;
            else if (c == 2) o = __expf(x) * aw;
            else if (c == 3) o = __expf(x) * ah;
            else             o = sigf(x);  // conf + 80 classes
            tile[sl * CH + c] = o;        // 2-way max bank aliasing
        }
    }
    __syncthreads();

    // ---- phase 2: contiguous ds_read_b128 + float4 stores ----
    const size_t obase = ((size_t)ba * SPATIAL + s0) * (size_t)CH;
    const int total = valid * CH;         // 21760 or 12240, mult of 4
    for (int k4 = tid * 4; k4 < total; k4 += NTHR * 4) {
        vfloat4 w = *(const vfloat4*)(tile + k4);
        *(vfloat4*)(out + obase + k4) = w;
    }
}

extern "C" void kernel_launch(void* const* d_in, const int* in_sizes, int n_in,
                              void* d_out, int out_size, void* d_ws, size_t ws_size,
                              hipStream_t stream) {
    const float* in = (const float*)d_in[0];
    float* out = (float*)d_out;
    yolo_kernel<<<NWG, NTHR, 0, stream>>>(in, out);
}